// Round 1
// baseline (45467.538 us; speedup 1.0000x reference)
//
#include <hip/hip_runtime.h>
#include <cstdint>
#include <cstddef>

#define NSTEPS 1024
#define TCHUNK 128
#define NCHUNK 8
#define BATCH 32
#define IDIM 128
#define HDIM 512
#define GDIM 2048
#define ODIM 10
#define NBLK 256

// ---------------------------------------------------------------------------
// proj: P[tt][n][b] = sum_k X[tt*32+b][k] * W[n][k] + bias[n]
// X: [TCHUNK*BATCH][K] row-major, W: [GDIM][K] row-major, P: [TCHUNK][GDIM][BATCH]
// ---------------------------------------------------------------------------
template<int K>
__launch_bounds__(256, 2)
__global__ void proj_kernel(const float* __restrict__ X,
                            const float* __restrict__ W,
                            const float* __restrict__ bias,
                            float* __restrict__ P) {
  __shared__ float Xs[8][132];
  __shared__ float Ws[8][132];
  const int tid = threadIdx.x;
  const int n0 = blockIdx.x * 128;
  const int m0 = blockIdx.y * 128;
  const int tx = tid & 15, ty = tid >> 4;
  const int lm = tid >> 1;
  const int kq = (tid & 1) * 4;
  float acc[8][8];
#pragma unroll
  for (int i = 0; i < 8; ++i)
#pragma unroll
    for (int j = 0; j < 8; ++j) acc[i][j] = 0.f;

  for (int k0 = 0; k0 < K; k0 += 8) {
    const float4 xv = *(const float4*)&X[(size_t)(m0 + lm) * K + k0 + kq];
    const float4 wv = *(const float4*)&W[(size_t)(n0 + lm) * K + k0 + kq];
    __syncthreads();
    Xs[kq + 0][lm] = xv.x; Xs[kq + 1][lm] = xv.y; Xs[kq + 2][lm] = xv.z; Xs[kq + 3][lm] = xv.w;
    Ws[kq + 0][lm] = wv.x; Ws[kq + 1][lm] = wv.y; Ws[kq + 2][lm] = wv.z; Ws[kq + 3][lm] = wv.w;
    __syncthreads();
#pragma unroll
    for (int kk = 0; kk < 8; ++kk) {
      float a[8], b[8];
      *(float4*)&a[0] = *(const float4*)&Xs[kk][ty * 8];
      *(float4*)&a[4] = *(const float4*)&Xs[kk][ty * 8 + 4];
      *(float4*)&b[0] = *(const float4*)&Ws[kk][tx * 8];
      *(float4*)&b[4] = *(const float4*)&Ws[kk][tx * 8 + 4];
#pragma unroll
      for (int i = 0; i < 8; ++i)
#pragma unroll
        for (int j = 0; j < 8; ++j) acc[i][j] += a[i] * b[j];
    }
  }
  const int mb = m0 + ty * 8;      // 8-aligned -> all 8 i share one t
  const int t  = mb >> 5;
  const int b0 = mb & 31;
#pragma unroll
  for (int j = 0; j < 8; ++j) {
    const int n = n0 + tx * 8 + j;
    const float bj = bias[n];
    float* dst = &P[((size_t)t * GDIM + n) * BATCH + b0];
#pragma unroll
    for (int i = 0; i < 8; ++i) dst[i] = acc[i][j] + bj;
  }
}

// ---------------------------------------------------------------------------
// scan: persistent LSTM recurrence over one T-chunk. 256 blocks, 1 block/CU
// (97KB LDS). Block bid owns h indices {bid*2, bid*2+1} => 8 gate rows.
// Gate row order r_local = q*2+j, global row = q*HDIM + bid*2 + j (q: i,f,g,o).
// ---------------------------------------------------------------------------
__launch_bounds__(256, 1)
__global__ void scan_kernel(const float* __restrict__ xp,    // [TCHUNK][GDIM][BATCH]
                            const float* __restrict__ Whh,   // [GDIM][HDIM]
                            float* __restrict__ hout,        // [TCHUNK][BATCH][HDIM]
                            float* __restrict__ hcur,        // [2][HDIM][BATCH] ping-pong
                            float* __restrict__ ccur,        // [HDIM][BATCH]
                            unsigned* __restrict__ bar,
                            int phase0, int first) {
  __shared__ float h_s[HDIM][BATCH];   // 64KB, k-major
  __shared__ float W_s[HDIM][8];       // 16KB, k-major
  __shared__ float red[16][256];       // 16KB, k-split partials
  __shared__ float gate_s[8][BATCH];   // 1KB

  const int tid = threadIdx.x;
  const int bid = blockIdx.x;

  // Load this block's 8 W_hh rows once; reused for all TCHUNK steps.
#pragma unroll
  for (int r = 0; r < 8; ++r) {
    const int row_g = (r >> 1) * HDIM + bid * 2 + (r & 1);
    for (int k = tid; k < HDIM; k += 256) W_s[k][r] = Whh[(size_t)row_g * HDIM + k];
  }

  // compute-phase role: thread = (p, s); p -> 4b x 4r tile, s -> 32-wide K slice
  const int p  = tid & 15;
  const int s  = tid >> 4;
  const int pb = (p & 7) * 4;
  const int pr = (p >> 3) * 4;
  // reduce-phase role: one gate pre-activation per thread
  const int out_r = tid >> 5;
  const int out_b = tid & 31;
  // update-phase role (tid < 64): one (hidx, b) cell
  const int uj = tid >> 5;
  const int ub = tid & 31;
  const int hidx = bid * 2 + uj;

  float c_st = 0.f;
  if (!first && tid < 64) c_st = ccur[hidx * BATCH + ub];

  unsigned phase = (unsigned)phase0;
  __syncthreads();

  for (int tt = 0; tt < TCHUNK; ++tt) {
    const int rp = tt & 1;
    // ---- stage h_prev (64KB) into LDS, coalesced float4 ----
    const float4* src = (const float4*)(hcur + (size_t)rp * HDIM * BATCH);
#pragma unroll
    for (int i = 0; i < 16; ++i) {
      const int idx = tid + 256 * i;           // float4 index, 4096 total
      const float4 v = src[idx];
      *(float4*)&h_s[idx >> 3][(idx & 7) * 4] = v;
    }
    __syncthreads();

    // ---- gates partials: acc[r][b] over this thread's 32-wide K slice ----
    float acc[4][4];
#pragma unroll
    for (int i = 0; i < 4; ++i)
#pragma unroll
      for (int j = 0; j < 4; ++j) acc[i][j] = 0.f;
    const int kbase = s * 32;
#pragma unroll
    for (int kk = 0; kk < 32; ++kk) {
      const float4 hv = *(const float4*)&h_s[kbase + kk][pb];
      const float4 wv = *(const float4*)&W_s[kbase + kk][pr];
      acc[0][0] += wv.x * hv.x; acc[0][1] += wv.x * hv.y; acc[0][2] += wv.x * hv.z; acc[0][3] += wv.x * hv.w;
      acc[1][0] += wv.y * hv.x; acc[1][1] += wv.y * hv.y; acc[1][2] += wv.y * hv.z; acc[1][3] += wv.y * hv.w;
      acc[2][0] += wv.z * hv.x; acc[2][1] += wv.z * hv.y; acc[2][2] += wv.z * hv.z; acc[2][3] += wv.z * hv.w;
      acc[3][0] += wv.w * hv.x; acc[3][1] += wv.w * hv.y; acc[3][2] += wv.w * hv.z; acc[3][3] += wv.w * hv.w;
    }
#pragma unroll
    for (int ri = 0; ri < 4; ++ri)
      *(float4*)&red[s][(pr + ri) * 32 + pb] =
          make_float4(acc[ri][0], acc[ri][1], acc[ri][2], acc[ri][3]);
    __syncthreads();

    // ---- reduce K-split partials, add xp, apply activation ----
    float pre = 0.f;
#pragma unroll
    for (int s2 = 0; s2 < 16; ++s2) pre += red[s2][tid];
    const int q = out_r >> 1;
    const int row_g = q * HDIM + bid * 2 + (out_r & 1);
    pre += xp[((size_t)tt * GDIM + row_g) * BATCH + out_b];
    const float act = (q == 2) ? tanhf(pre) : 1.f / (1.f + __expf(-pre));
    gate_s[out_r][out_b] = act;
    __syncthreads();

    // ---- c/h update (wave 0 only; 2 hidx x 32 b) ----
    if (tid < 64) {
      const float ig = gate_s[0 + uj][ub];
      const float fg = gate_s[2 + uj][ub];
      const float gg = gate_s[4 + uj][ub];
      const float og = gate_s[6 + uj][ub];
      c_st = fg * c_st + ig * gg;
      const float h = og * tanhf(c_st);
      hcur[(size_t)(1 - rp) * HDIM * BATCH + hidx * BATCH + ub] = h;
      hout[(size_t)tt * BATCH * HDIM + ub * HDIM + hidx] = h;
    }
    __syncthreads();

    // ---- grid barrier (monotonic counter, device scope) ----
    if (tid == 0) {
      __threadfence();                 // release: h stores (wave 0) -> visible
      atomicAdd(bar, 1u);
      ++phase;
      const unsigned target = phase * NBLK;
      while (__hip_atomic_load(bar, __ATOMIC_RELAXED, __HIP_MEMORY_SCOPE_AGENT) < target) {
        __builtin_amdgcn_s_sleep(1);
      }
      __threadfence();                 // acquire: invalidate stale h lines
    }
    __syncthreads();
  }
  if (tid < 64) ccur[hidx * BATCH + ub] = c_st;
}

// ---------------------------------------------------------------------------
// head: logits = h2 @ W3^T + b3 ; softmax over 10. One wave per row.
// ---------------------------------------------------------------------------
__launch_bounds__(256, 2)
__global__ void head_kernel(const float* __restrict__ h2,   // [rows][HDIM]
                            const float* __restrict__ W3,   // [ODIM][HDIM]
                            const float* __restrict__ b3,
                            float* __restrict__ outp) {     // [rows][ODIM]
  const int tid = threadIdx.x;
  const int lane = tid & 63;
  const int wv = tid >> 6;
  const int row = blockIdx.x * 4 + wv;
  const float* hrow = &h2[(size_t)row * HDIM];
  float hreg[8];
  *(float4*)&hreg[0] = *(const float4*)&hrow[lane * 8];
  *(float4*)&hreg[4] = *(const float4*)&hrow[lane * 8 + 4];
  float logit[ODIM];
#pragma unroll
  for (int o = 0; o < ODIM; ++o) {
    const float* wrow = &W3[o * HDIM + lane * 8];
    float w[8];
    *(float4*)&w[0] = *(const float4*)&wrow[0];
    *(float4*)&w[4] = *(const float4*)&wrow[4];
    float pp = 0.f;
#pragma unroll
    for (int j = 0; j < 8; ++j) pp += hreg[j] * w[j];
#pragma unroll
    for (int off = 32; off > 0; off >>= 1) pp += __shfl_xor(pp, off);
    logit[o] = pp + b3[o];
  }
  float m = logit[0];
#pragma unroll
  for (int o = 1; o < ODIM; ++o) m = fmaxf(m, logit[o]);
  float ssum = 0.f;
#pragma unroll
  for (int o = 0; o < ODIM; ++o) { logit[o] = __expf(logit[o] - m); ssum += logit[o]; }
  const float inv = 1.f / ssum;
  if (lane == 0) {
    float* dst = &outp[(size_t)row * ODIM];
#pragma unroll
    for (int o = 0; o < ODIM; ++o) dst[o] = logit[o] * inv;
  }
}

// ---------------------------------------------------------------------------
extern "C" void kernel_launch(void* const* d_in, const int* in_sizes, int n_in,
                              void* d_out, int out_size, void* d_ws, size_t ws_size,
                              hipStream_t stream) {
  const float* data  = (const float*)d_in[0];
  const float* W_ih1 = (const float*)d_in[1];
  const float* W_hh1 = (const float*)d_in[2];
  const float* b1    = (const float*)d_in[3];
  const float* W_ih2 = (const float*)d_in[4];
  const float* W_hh2 = (const float*)d_in[5];
  const float* b2    = (const float*)d_in[6];
  const float* W3    = (const float*)d_in[7];
  const float* b3    = (const float*)d_in[8];
  float* outp = (float*)d_out;

  char* ws = (char*)d_ws;
  size_t off = 0;
  float* xp    = (float*)(ws + off); off += (size_t)TCHUNK * GDIM * BATCH * 4;   // 32MB
  float* h1c   = (float*)(ws + off); off += (size_t)TCHUNK * BATCH * HDIM * 4;   // 8MB
  float* h2c   = (float*)(ws + off); off += (size_t)TCHUNK * BATCH * HDIM * 4;   // 8MB
  float* hcur1 = (float*)(ws + off); off += 2 * HDIM * BATCH * 4;
  float* hcur2 = (float*)(ws + off); off += 2 * HDIM * BATCH * 4;
  float* ccur1 = (float*)(ws + off); off += HDIM * BATCH * 4;
  float* ccur2 = (float*)(ws + off); off += HDIM * BATCH * 4;
  unsigned* bar1 = (unsigned*)(ws + off); off += 256;
  unsigned* bar2 = (unsigned*)(ws + off); off += 256;
  if (off > ws_size) return;  // workspace too small: bail (output stays invalid)

  hipMemsetAsync(hcur1, 0, HDIM * BATCH * 4, stream);   // parity-0 buffer = h0 = 0
  hipMemsetAsync(hcur2, 0, HDIM * BATCH * 4, stream);
  hipMemsetAsync(bar1, 0, 256, stream);
  hipMemsetAsync(bar2, 0, 256, stream);

  const dim3 pgrid(GDIM / 128, (TCHUNK * BATCH) / 128);
  for (int c = 0; c < NCHUNK; ++c) {
    const float* xin = data + (size_t)c * TCHUNK * BATCH * IDIM;
    proj_kernel<IDIM><<<pgrid, 256, 0, stream>>>(xin, W_ih1, b1, xp);
    scan_kernel<<<NBLK, 256, 0, stream>>>(xp, W_hh1, h1c, hcur1, ccur1, bar1,
                                          c * TCHUNK, c == 0);
    proj_kernel<HDIM><<<pgrid, 256, 0, stream>>>(h1c, W_ih2, b2, xp);
    scan_kernel<<<NBLK, 256, 0, stream>>>(xp, W_hh2, h2c, hcur2, ccur2, bar2,
                                          c * TCHUNK, c == 0);
    head_kernel<<<(TCHUNK * BATCH) / 4, 256, 0, stream>>>(
        h2c, W3, b3, outp + (size_t)c * TCHUNK * BATCH * ODIM);
  }
}